// Round 3
// baseline (3477.724 us; speedup 1.0000x reference)
//
#include <hip/hip_runtime.h>

#define S  8     // samples per block
#define NT 512   // threads per block (8 waves)

#if __has_builtin(__builtin_amdgcn_exp2f)
__device__ __forceinline__ float fexp(float x) { return __builtin_amdgcn_exp2f(x * 1.4426950408889634f); }
#else
__device__ __forceinline__ float fexp(float x) { return __expf(x); }
#endif
#if __has_builtin(__builtin_amdgcn_rcpf)
__device__ __forceinline__ float frcp(float x) { return __builtin_amdgcn_rcpf(x); }
#else
__device__ __forceinline__ float frcp(float x) { return 1.0f / x; }
#endif

__device__ __forceinline__ float sigm(float x)  { return frcp(1.0f + fexp(-x)); }
__device__ __forceinline__ float tanh_(float x) { return 1.0f - 2.0f * frcp(1.0f + fexp(2.0f * x)); }
__device__ __forceinline__ float lrelu(float x) { return x > 0.0f ? x : 0.01f * x; }

// acc += dot8(wt, [ha|hb])   -- NB: parameter must NOT be named `w`
// (macro substitution would rewrite the member access `.w`!)
#define DOT8(acc, wt, ha, hb)                                                     \
    acc += (wt)[0]*(ha).x + (wt)[1]*(ha).y + (wt)[2]*(ha).z + (wt)[3]*(ha).w      \
         + (wt)[4]*(hb).x + (wt)[5]*(hb).y + (wt)[6]*(hb).z + (wt)[7]*(hb).w

__global__ __launch_bounds__(NT, 2) void gen_kernel(
    const float* __restrict__ noise,
    const float* __restrict__ w_ih0, const float* __restrict__ w_hh0,
    const float* __restrict__ b_ih0, const float* __restrict__ b_hh0,
    const float* __restrict__ w_ih1, const float* __restrict__ w_hh1,
    const float* __restrict__ b_ih1, const float* __restrict__ b_hh1,
    const float* __restrict__ w_ih2, const float* __restrict__ w_hh2,
    const float* __restrict__ b_ih2, const float* __restrict__ b_hh2,
    const float* __restrict__ fc1_w, const float* __restrict__ fc1_b,
    const float* __restrict__ fc2_w, const float* __restrict__ fc2_b,
    const float* __restrict__ fc3_w, const float* __restrict__ fc3_b,
    const int*   __restrict__ flow_len_p,
    float* __restrict__ out)
{
    // (sample, k-slice q, hidden j) -> float4 of 4 gate partials
    __shared__ float4 s_part[S][8][64];                               // 64 KB
    __shared__ float  s_h[3][S][64] __attribute__((aligned(16)));     // 6 KB
    __shared__ float  s_x[S][4];
    __shared__ float  s_bias[3][256];                                 // b_ih + b_hh
    __shared__ float  s_fc1b[32];
    __shared__ float  s_pfc[S][64];
    __shared__ float  s_y1[S][32];
    __shared__ float  s_y2[S][16];
    __shared__ float  s_fc2wT[32 * 16];                               // [k][o]
    __shared__ float  s_fc2b[16];
    __shared__ float  s_fc3wT[16 * 4];                                // [k][d], d padded to 4
    __shared__ float  s_fc3b[4];

    const int tid  = threadIdx.x;
    const int j    = tid & 63;   // hidden unit / lane
    const int q    = tid >> 6;   // k-slice role (GEMV) == sample role (activation)
    const int k0   = q * 8;
    const int base = blockIdx.x * S;
    const int T    = flow_len_p[0];

    // ---------------- register-stationary weights ----------------
    float wh0[4][8], wi1[4][8], wh1[4][8], wi2[4][8], wh2[4][8];
    float wi0[4][3];
#define LOAD_ROW8(dst, src)                                             \
    do {                                                                \
        const float4* p4 = (const float4*)((src) + r * 64 + k0);        \
        float4 va = p4[0], vb = p4[1];                                  \
        (dst)[0]=va.x; (dst)[1]=va.y; (dst)[2]=va.z; (dst)[3]=va.w;     \
        (dst)[4]=vb.x; (dst)[5]=vb.y; (dst)[6]=vb.z; (dst)[7]=vb.w;     \
    } while (0)

#pragma unroll
    for (int g = 0; g < 4; ++g) {
        const int r = g * 64 + j;
        LOAD_ROW8(wh0[g], w_hh0);
        LOAD_ROW8(wi1[g], w_ih1);
        LOAD_ROW8(wh1[g], w_hh1);
        LOAD_ROW8(wi2[g], w_ih2);
        LOAD_ROW8(wh2[g], w_hh2);
        wi0[g][0] = w_ih0[r * 3 + 0];
        wi0[g][1] = w_ih0[r * 3 + 1];
        wi0[g][2] = w_ih0[r * 3 + 2];
    }
    // fc1 slice: thread j -> (o1 = j&31, hf = j>>5), k in [hf*32, hf*32+32)
    const int o1 = j & 31, hf = j >> 5;
    float wfc1[32];
#pragma unroll
    for (int kk4 = 0; kk4 < 8; ++kk4) {
        float4 va = ((const float4*)(fc1_w + o1 * 64 + hf * 32))[kk4];
        wfc1[kk4*4+0] = va.x; wfc1[kk4*4+1] = va.y;
        wfc1[kk4*4+2] = va.z; wfc1[kk4*4+3] = va.w;
    }

    // ---------------- LDS init ----------------
    for (int idx = tid; idx < 3 * 256; idx += NT) {
        int l = idx >> 8, r = idx & 255;
        const float* bi = (l == 0) ? b_ih0 : (l == 1) ? b_ih1 : b_ih2;
        const float* bh = (l == 0) ? b_hh0 : (l == 1) ? b_hh1 : b_hh2;
        s_bias[l][r] = bi[r] + bh[r];
    }
    for (int idx = tid; idx < 3 * S * 64; idx += NT) ((float*)s_h)[idx] = 0.0f;
    if (tid < S * 4) {
        int s = tid >> 2, d = tid & 3;
        s_x[s][d] = (d < 3) ? noise[(base + s) * 3 + d] : 0.0f;
    }
    if (tid < 32) s_fc1b[tid] = fc1_b[tid];
    { int k = tid >> 4, o = tid & 15; s_fc2wT[tid] = fc2_w[o * 32 + k]; }  // tid<512 == 32*16
    if (tid < 16) s_fc2b[tid] = fc2_b[tid];
    if (tid < 64) { int k = tid >> 2, d = tid & 3; s_fc3wT[tid] = (d < 3) ? fc3_w[d * 16 + k] : 0.0f; }
    if (tid < 4)  s_fc3b[tid] = (tid < 3) ? fc3_b[tid] : 0.0f;

    float c0 = 0.0f, c1 = 0.0f, c2 = 0.0f;
    __syncthreads();

#define ACT_PHASE(L, CREG)                                                        \
    do {                                                                          \
        float4 rr = s_part[q][0][j];                                              \
        _Pragma("unroll")                                                         \
        for (int qq = 1; qq < 8; ++qq) {                                          \
            float4 pp = s_part[q][qq][j];                                         \
            rr.x += pp.x; rr.y += pp.y; rr.z += pp.z; rr.w += pp.w;               \
        }                                                                         \
        float gi = rr.x + s_bias[L][j];                                           \
        float gf = rr.y + s_bias[L][64 + j];                                      \
        float gg = rr.z + s_bias[L][128 + j];                                     \
        float go = rr.w + s_bias[L][192 + j];                                     \
        CREG = sigm(gf) * CREG + sigm(gi) * tanh_(gg);                            \
        s_h[L][q][j] = sigm(go) * tanh_(CREG);                                    \
    } while (0)

    // ---------------- time loop ----------------
    for (int t = 0; t < T; ++t) {
        // A: layer0 partials  (gates = w_ih0 @ x + w_hh0 @ h0)
        for (int s = 0; s < S; ++s) {
            float a0, a1, a2, a3;
            if (q == 0) {
                float x0 = s_x[s][0], x1 = s_x[s][1], x2 = s_x[s][2];
                a0 = wi0[0][0]*x0 + wi0[0][1]*x1 + wi0[0][2]*x2;
                a1 = wi0[1][0]*x0 + wi0[1][1]*x1 + wi0[1][2]*x2;
                a2 = wi0[2][0]*x0 + wi0[2][1]*x1 + wi0[2][2]*x2;
                a3 = wi0[3][0]*x0 + wi0[3][1]*x1 + wi0[3][2]*x2;
            } else { a0 = a1 = a2 = a3 = 0.0f; }
            const float4 ha = *(const float4*)&s_h[0][s][k0];
            const float4 hb = *(const float4*)&s_h[0][s][k0 + 4];
            DOT8(a0, wh0[0], ha, hb);
            DOT8(a1, wh0[1], ha, hb);
            DOT8(a2, wh0[2], ha, hb);
            DOT8(a3, wh0[3], ha, hb);
            s_part[s][q][j] = make_float4(a0, a1, a2, a3);
        }
        __syncthreads();
        // B: layer0 reduce + activate  (thread -> sample q, unit j)
        ACT_PHASE(0, c0);
        __syncthreads();
        // C: layer1 partials (x = h0, h = h1)
        for (int s = 0; s < S; ++s) {
            const float4 xa = *(const float4*)&s_h[0][s][k0];
            const float4 xb = *(const float4*)&s_h[0][s][k0 + 4];
            const float4 ha = *(const float4*)&s_h[1][s][k0];
            const float4 hb = *(const float4*)&s_h[1][s][k0 + 4];
            float a0 = 0, a1 = 0, a2 = 0, a3 = 0;
            DOT8(a0, wi1[0], xa, xb); DOT8(a0, wh1[0], ha, hb);
            DOT8(a1, wi1[1], xa, xb); DOT8(a1, wh1[1], ha, hb);
            DOT8(a2, wi1[2], xa, xb); DOT8(a2, wh1[2], ha, hb);
            DOT8(a3, wi1[3], xa, xb); DOT8(a3, wh1[3], ha, hb);
            s_part[s][q][j] = make_float4(a0, a1, a2, a3);
        }
        __syncthreads();
        // D: layer1 activate
        ACT_PHASE(1, c1);
        __syncthreads();
        // E: layer2 partials (x = h1, h = h2)
        for (int s = 0; s < S; ++s) {
            const float4 xa = *(const float4*)&s_h[1][s][k0];
            const float4 xb = *(const float4*)&s_h[1][s][k0 + 4];
            const float4 ha = *(const float4*)&s_h[2][s][k0];
            const float4 hb = *(const float4*)&s_h[2][s][k0 + 4];
            float a0 = 0, a1 = 0, a2 = 0, a3 = 0;
            DOT8(a0, wi2[0], xa, xb); DOT8(a0, wh2[0], ha, hb);
            DOT8(a1, wi2[1], xa, xb); DOT8(a1, wh2[1], ha, hb);
            DOT8(a2, wi2[2], xa, xb); DOT8(a2, wh2[2], ha, hb);
            DOT8(a3, wi2[3], xa, xb); DOT8(a3, wh2[3], ha, hb);
            s_part[s][q][j] = make_float4(a0, a1, a2, a3);
        }
        __syncthreads();
        // F: layer2 activate
        ACT_PHASE(2, c2);
        __syncthreads();
        // G1: fc1 partial dot (all 512 threads: sample q, out o1, k-half hf)
        {
            float acc = 0.0f;
#pragma unroll
            for (int kk4 = 0; kk4 < 8; ++kk4) {
                float4 h4 = *(const float4*)&s_h[2][q][hf * 32 + kk4 * 4];
                acc += wfc1[kk4*4+0]*h4.x + wfc1[kk4*4+1]*h4.y
                     + wfc1[kk4*4+2]*h4.z + wfc1[kk4*4+3]*h4.w;
            }
            s_pfc[q][j] = acc;
        }
        __syncthreads();
        // G2: fc1 combine + leaky
        if (tid < 256) {
            int s = tid >> 5, o = tid & 31;
            s_y1[s][o] = lrelu(s_pfc[s][o] + s_pfc[s][32 + o] + s_fc1b[o]);
        }
        __syncthreads();
        // G3: fc2
        if (tid < 128) {
            int s = tid >> 4, o = tid & 15;
            float acc = s_fc2b[o];
#pragma unroll
            for (int k = 0; k < 32; ++k) acc += s_fc2wT[k * 16 + o] * s_y1[s][k];
            s_y2[s][o] = lrelu(acc);
        }
        __syncthreads();
        // G4: fc3 -> output + next x
        if (tid < 32) {
            int s = tid >> 2, d = tid & 3;
            if (d < 3) {
                float acc = s_fc3b[d];
#pragma unroll
                for (int k = 0; k < 16; ++k) acc += s_fc3wT[k * 4 + d] * s_y2[s][k];
                float y = lrelu(acc);
                s_x[s][d] = y;
                out[((size_t)(base + s) * T + t) * 3 + d] = y;
            }
        }
        __syncthreads();
    }
}

extern "C" void kernel_launch(void* const* d_in, const int* in_sizes, int n_in,
                              void* d_out, int out_size, void* d_ws, size_t ws_size,
                              hipStream_t stream) {
    const float* noise = (const float*)d_in[0];
    const float* w_ih0 = (const float*)d_in[1];
    const float* w_hh0 = (const float*)d_in[2];
    const float* b_ih0 = (const float*)d_in[3];
    const float* b_hh0 = (const float*)d_in[4];
    const float* w_ih1 = (const float*)d_in[5];
    const float* w_hh1 = (const float*)d_in[6];
    const float* b_ih1 = (const float*)d_in[7];
    const float* b_hh1 = (const float*)d_in[8];
    const float* w_ih2 = (const float*)d_in[9];
    const float* w_hh2 = (const float*)d_in[10];
    const float* b_ih2 = (const float*)d_in[11];
    const float* b_hh2 = (const float*)d_in[12];
    const float* fc1w  = (const float*)d_in[13];
    const float* fc1b  = (const float*)d_in[14];
    const float* fc2w  = (const float*)d_in[15];
    const float* fc2b  = (const float*)d_in[16];
    const float* fc3w  = (const float*)d_in[17];
    const float* fc3b  = (const float*)d_in[18];
    const int*   flp   = (const int*)d_in[19];

    gen_kernel<<<dim3(2048 / S), dim3(NT), 0, stream>>>(
        noise, w_ih0, w_hh0, b_ih0, b_hh0,
        w_ih1, w_hh1, b_ih1, b_hh1,
        w_ih2, w_hh2, b_ih2, b_hh2,
        fc1w, fc1b, fc2w, fc2b, fc3w, fc3b,
        flp, (float*)d_out);
}